// Round 1
// baseline (1550.312 us; speedup 1.0000x reference)
//
#include <hip/hip_runtime.h>

#define NN 100000
#define EE 3200000
#define HH 128
#define CC 40

// rp[i] = lower_bound(edge_dst, i) — edge_dst is sorted.
__global__ void build_rp(const int* __restrict__ dst, int* __restrict__ rp) {
    int i = blockIdx.x * blockDim.x + threadIdx.x;
    if (i > NN) return;
    int lo = 0, hi = EE;
    while (lo < hi) {
        int mid = (lo + hi) >> 1;
        if (dst[mid] < i) lo = mid + 1; else hi = mid;
    }
    rp[i] = lo;
}

// One block (128 threads) per node; thread t owns feature t.
// acc += w[e] * h[src[e]][t] over this node's edge range. No atomics.
__global__ void spmm128(const float* __restrict__ h, const int* __restrict__ src,
                        const float* __restrict__ w, const int* __restrict__ rp,
                        float* __restrict__ out) {
    int i = blockIdx.x;
    int t = threadIdx.x;
    int e0 = rp[i], e1 = rp[i + 1];
    float acc = 0.f;
    for (int e = e0; e < e1; ++e) {
        int s = src[e];
        acc = fmaf(w[e], h[s * HH + t], acc);
    }
    out[i * HH + t] = acc;
}

// out[r][c] = tanh(dot(A[r][:], W[:][c])), A rows staged in LDS.
template <int NOUT>
__global__ void gemm_tanh(const float* __restrict__ A, const float* __restrict__ W,
                          float* __restrict__ out) {
    constexpr int ROWS = 16;
    __shared__ float As[ROWS][HH];
    int r0 = blockIdx.x * ROWS;
    for (int idx = threadIdx.x; idx < ROWS * HH; idx += 256) {
        int r = idx >> 7, c = idx & (HH - 1);
        int gr = r0 + r;
        As[r][c] = (gr < NN) ? A[gr * HH + c] : 0.f;
    }
    __syncthreads();
    for (int o = threadIdx.x; o < ROWS * NOUT; o += 256) {
        int r = o / NOUT, c = o - r * NOUT;
        float acc = 0.f;
#pragma unroll 8
        for (int k = 0; k < HH; ++k)
            acc = fmaf(As[r][k], W[k * NOUT + c], acc);
        int gr = r0 + r;
        if (gr < NN) out[gr * NOUT + c] = tanhf(acc);
    }
}

extern "C" void kernel_launch(void* const* d_in, const int* in_sizes, int n_in,
                              void* d_out, int out_size, void* d_ws, size_t ws_size,
                              hipStream_t stream) {
    const float* x    = (const float*)d_in[0];
    const int*   esrc = (const int*)d_in[1];
    const int*   edst = (const int*)d_in[2];
    const float* ew   = (const float*)d_in[3];
    const float* W0   = (const float*)d_in[4];
    const float* W1   = (const float*)d_in[5];
    const float* W2   = (const float*)d_in[6];
    float* out = (float*)d_out;

    char* ws = (char*)d_ws;
    int* rp = (int*)ws;
    size_t rp_bytes = (((size_t)(NN + 1) * sizeof(int)) + 255) & ~(size_t)255;
    float* buf1 = (float*)(ws + rp_bytes);              // [NN, HH]
    float* buf2 = buf1 + (size_t)NN * HH;               // [NN, HH]

    build_rp<<<(NN + 256) / 256, 256, 0, stream>>>(edst, rp);

    // layer 1
    spmm128<<<NN, 128, 0, stream>>>(x, esrc, ew, rp, buf1);
    gemm_tanh<HH><<<(NN + 15) / 16, 256, 0, stream>>>(buf1, W0, buf2);
    // layer 2
    spmm128<<<NN, 128, 0, stream>>>(buf2, esrc, ew, rp, buf1);
    gemm_tanh<HH><<<(NN + 15) / 16, 256, 0, stream>>>(buf1, W1, buf2);
    // output layer
    spmm128<<<NN, 128, 0, stream>>>(buf2, esrc, ew, rp, buf1);
    gemm_tanh<CC><<<(NN + 15) / 16, 256, 0, stream>>>(buf1, W2, out);
}

// Round 2
// 584.215 us; speedup vs baseline: 2.6537x; 2.6537x over previous
//
#include <hip/hip_runtime.h>
#include <hip/hip_fp16.h>

#define NN 100000
#define EE 3200000
#define HH 128
#define CC 40

// rp[i] = lower_bound(edge_dst, i) — edge_dst is sorted.
__global__ void build_rp(const int* __restrict__ dst, int* __restrict__ rp) {
    int i = blockIdx.x * blockDim.x + threadIdx.x;
    if (i > NN) return;
    int lo = 0, hi = EE;
    while (lo < hi) {
        int mid = (lo + hi) >> 1;
        if (dst[mid] < i) lo = mid + 1; else hi = mid;
    }
    rp[i] = lo;
}

// f32 -> fp16, 8 elements/thread. n must be divisible by 8.
__global__ __launch_bounds__(256) void f32_to_f16(const float* __restrict__ in,
                                                  __half* __restrict__ out, int n) {
    int base = (blockIdx.x * 256 + threadIdx.x) * 8;
    if (base >= n) return;
    float4 a = *(const float4*)(in + base);
    float4 b = *(const float4*)(in + base + 4);
    __half2 h[4];
    h[0] = __floats2half2_rn(a.x, a.y);
    h[1] = __floats2half2_rn(a.z, a.w);
    h[2] = __floats2half2_rn(b.x, b.y);
    h[3] = __floats2half2_rn(b.z, b.w);
    *(float4*)(out + base) = *(float4*)h;
}

// One wave (64 lanes) per node, 4 nodes per block. Lane t owns features 2t,2t+1.
// fp16 gather rows (256B/edge), f32 accumulate, f32 out [NN][128].
__global__ __launch_bounds__(256) void spmm_h16(const __half* __restrict__ h,
                                                const int* __restrict__ src,
                                                const float* __restrict__ w,
                                                const int* __restrict__ rp,
                                                float* __restrict__ out) {
    int node = blockIdx.x * 4 + (threadIdx.x >> 6);
    int t = threadIdx.x & 63;
    if (node >= NN) return;
    int e0 = __builtin_amdgcn_readfirstlane(rp[node]);
    int e1 = __builtin_amdgcn_readfirstlane(rp[node + 1]);
    const __half2* __restrict__ h2 = (const __half2*)h;
    float accx = 0.f, accy = 0.f;
    int e = e0;
    for (; e + 4 <= e1; e += 4) {
        int s0 = src[e], s1 = src[e + 1], s2 = src[e + 2], s3 = src[e + 3];
        float w0 = w[e], w1 = w[e + 1], w2 = w[e + 2], w3 = w[e + 3];
        __half2 r0 = h2[(size_t)s0 * 64 + t];
        __half2 r1 = h2[(size_t)s1 * 64 + t];
        __half2 r2 = h2[(size_t)s2 * 64 + t];
        __half2 r3 = h2[(size_t)s3 * 64 + t];
        float2 f0 = __half22float2(r0), f1 = __half22float2(r1);
        float2 f2 = __half22float2(r2), f3 = __half22float2(r3);
        accx = fmaf(w0, f0.x, accx); accy = fmaf(w0, f0.y, accy);
        accx = fmaf(w1, f1.x, accx); accy = fmaf(w1, f1.y, accy);
        accx = fmaf(w2, f2.x, accx); accy = fmaf(w2, f2.y, accy);
        accx = fmaf(w3, f3.x, accx); accy = fmaf(w3, f3.y, accy);
    }
    for (; e < e1; ++e) {
        int s = src[e]; float ww = w[e];
        float2 f = __half22float2(h2[(size_t)s * 64 + t]);
        accx = fmaf(ww, f.x, accx); accy = fmaf(ww, f.y, accy);
    }
    *(float2*)(out + (size_t)node * HH + 2 * t) = make_float2(accx, accy);
}

// spmm over 40-wide fp16 rows (80B/edge) + tanh, f32 out [NN][40].
__global__ __launch_bounds__(256) void spmm40_tanh(const __half* __restrict__ g,
                                                   const int* __restrict__ src,
                                                   const float* __restrict__ w,
                                                   const int* __restrict__ rp,
                                                   float* __restrict__ out) {
    int node = blockIdx.x * 4 + (threadIdx.x >> 6);
    int t = threadIdx.x & 63;
    if (node >= NN) return;
    int e0 = __builtin_amdgcn_readfirstlane(rp[node]);
    int e1 = __builtin_amdgcn_readfirstlane(rp[node + 1]);
    const __half2* __restrict__ g2 = (const __half2*)g;
    int tt = t < 20 ? t : 0;  // clamp lanes >=20 (results discarded)
    float accx = 0.f, accy = 0.f;
    int e = e0;
    for (; e + 4 <= e1; e += 4) {
        int s0 = src[e], s1 = src[e + 1], s2 = src[e + 2], s3 = src[e + 3];
        float w0 = w[e], w1 = w[e + 1], w2 = w[e + 2], w3 = w[e + 3];
        float2 f0 = __half22float2(g2[(size_t)s0 * 20 + tt]);
        float2 f1 = __half22float2(g2[(size_t)s1 * 20 + tt]);
        float2 f2 = __half22float2(g2[(size_t)s2 * 20 + tt]);
        float2 f3 = __half22float2(g2[(size_t)s3 * 20 + tt]);
        accx = fmaf(w0, f0.x, accx); accy = fmaf(w0, f0.y, accy);
        accx = fmaf(w1, f1.x, accx); accy = fmaf(w1, f1.y, accy);
        accx = fmaf(w2, f2.x, accx); accy = fmaf(w2, f2.y, accy);
        accx = fmaf(w3, f3.x, accx); accy = fmaf(w3, f3.y, accy);
    }
    for (; e < e1; ++e) {
        int s = src[e]; float ww = w[e];
        float2 f = __half22float2(g2[(size_t)s * 20 + tt]);
        accx = fmaf(ww, f.x, accx); accy = fmaf(ww, f.y, accy);
    }
    if (t < 20)
        *(float2*)(out + (size_t)node * CC + 2 * t) = make_float2(tanhf(accx), tanhf(accy));
}

// C[r][c] = tanh(A[r][:] @ W[:][c]) -> fp16 out. 128x128 tile, 8x8/thread.
__global__ __launch_bounds__(256) void gemm128_tanh(const float* __restrict__ A,
                                                    const float* __restrict__ W,
                                                    __half* __restrict__ out) {
    __shared__ float As[16][HH];
    __shared__ float Ws[16][HH];
    int tid = threadIdx.x;
    int r0 = blockIdx.x * 128;
    int ty = tid >> 4, tx = tid & 15;
    int m = tid >> 1, kk = (tid & 1) * 8;
    int kw = tid >> 4, n8 = (tid & 15) * 8;
    float acc[8][8] = {};
    for (int k0 = 0; k0 < HH; k0 += 16) {
        float4 a0 = {0, 0, 0, 0}, a1 = {0, 0, 0, 0};
        int gr = r0 + m;
        if (gr < NN) {
            a0 = *(const float4*)(A + (size_t)gr * HH + k0 + kk);
            a1 = *(const float4*)(A + (size_t)gr * HH + k0 + kk + 4);
        }
        float4 b0 = *(const float4*)(W + (size_t)(k0 + kw) * HH + n8);
        float4 b1 = *(const float4*)(W + (size_t)(k0 + kw) * HH + n8 + 4);
        __syncthreads();
        As[kk + 0][m] = a0.x; As[kk + 1][m] = a0.y; As[kk + 2][m] = a0.z; As[kk + 3][m] = a0.w;
        As[kk + 4][m] = a1.x; As[kk + 5][m] = a1.y; As[kk + 6][m] = a1.z; As[kk + 7][m] = a1.w;
        *(float4*)&Ws[kw][n8] = b0;
        *(float4*)&Ws[kw][n8 + 4] = b1;
        __syncthreads();
#pragma unroll
        for (int k = 0; k < 16; ++k) {
            float av[8], bv[8];
            *(float4*)&av[0] = *(const float4*)&As[k][ty * 8];
            *(float4*)&av[4] = *(const float4*)&As[k][ty * 8 + 4];
            *(float4*)&bv[0] = *(const float4*)&Ws[k][tx * 8];
            *(float4*)&bv[4] = *(const float4*)&Ws[k][tx * 8 + 4];
#pragma unroll
            for (int i = 0; i < 8; ++i)
#pragma unroll
                for (int j = 0; j < 8; ++j)
                    acc[i][j] = fmaf(av[i], bv[j], acc[i][j]);
        }
    }
#pragma unroll
    for (int i = 0; i < 8; ++i) {
        int gr = r0 + ty * 8 + i;
        if (gr < NN) {
            __half2 hv[4];
#pragma unroll
            for (int j = 0; j < 4; ++j)
                hv[j] = __floats2half2_rn(tanhf(acc[i][2 * j]), tanhf(acc[i][2 * j + 1]));
            *(float4*)(out + (size_t)gr * HH + tx * 8) = *(float4*)hv;
        }
    }
}

// g = Ah(fp16) @ W2 (no tanh) -> fp16 [NN][40]. 128 rows/block, 4x5 per thread.
__global__ __launch_bounds__(256) void gemm40_f16(const __half* __restrict__ Ah,
                                                  const float* __restrict__ W,
                                                  __half* __restrict__ out) {
    __shared__ float As[16][HH];
    __shared__ float Wsf[HH * CC];
    int tid = threadIdx.x;
    int r0 = blockIdx.x * 128;
    int ty = tid >> 3, tx = tid & 7;  // ty 0..31 -> 4 rows; tx 0..7 -> 5 cols
    // stage all of W2
    for (int idx = tid; idx < HH * CC; idx += 256) Wsf[idx] = W[idx];
    int m = tid >> 1, kk = (tid & 1) * 8;
    float acc[4][5] = {};
    for (int k0 = 0; k0 < HH; k0 += 16) {
        __half2 av16[4] = {};
        int gr = r0 + m;
        if (gr < NN)
            *(float4*)av16 = *(const float4*)(Ah + (size_t)gr * HH + k0 + kk);
        __syncthreads();
#pragma unroll
        for (int j = 0; j < 4; ++j) {
            float2 f = __half22float2(av16[j]);
            As[kk + 2 * j][m] = f.x;
            As[kk + 2 * j + 1][m] = f.y;
        }
        __syncthreads();
#pragma unroll
        for (int k = 0; k < 16; ++k) {
            float av[4];
            *(float4*)av = *(const float4*)&As[k][ty * 4];
            const float* wr = &Wsf[(k0 + k) * CC + tx * 5];
#pragma unroll
            for (int i = 0; i < 4; ++i)
#pragma unroll
                for (int j = 0; j < 5; ++j)
                    acc[i][j] = fmaf(av[i], wr[j], acc[i][j]);
        }
    }
#pragma unroll
    for (int i = 0; i < 4; ++i) {
        int gr = r0 + ty * 4 + i;
        if (gr < NN) {
#pragma unroll
            for (int j = 0; j < 5; ++j)
                out[(size_t)gr * CC + tx * 5 + j] = __float2half_rn(acc[i][j]);
        }
    }
}

extern "C" void kernel_launch(void* const* d_in, const int* in_sizes, int n_in,
                              void* d_out, int out_size, void* d_ws, size_t ws_size,
                              hipStream_t stream) {
    const float* x    = (const float*)d_in[0];
    const int*   esrc = (const int*)d_in[1];
    const int*   edst = (const int*)d_in[2];
    const float* ew   = (const float*)d_in[3];
    const float* W0   = (const float*)d_in[4];
    const float* W1   = (const float*)d_in[5];
    const float* W2   = (const float*)d_in[6];
    float* out = (float*)d_out;

    char* ws = (char*)d_ws;
    size_t off = 0;
    int* rp = (int*)(ws + off);           off += (((size_t)(NN + 1) * 4) + 511) & ~(size_t)511;
    __half* hbuf = (__half*)(ws + off);   off += (size_t)NN * HH * sizeof(__half);   // fp16 [NN][128]
    float* sbuf = (float*)(ws + off);     off += (size_t)NN * HH * sizeof(float);    // f32  [NN][128]
    __half* gbuf = (__half*)(ws + off);   off += (size_t)NN * CC * sizeof(__half);   // fp16 [NN][40]

    build_rp<<<(NN + 256) / 256, 256, 0, stream>>>(edst, rp);
    f32_to_f16<<<(NN * HH) / (256 * 8), 256, 0, stream>>>(x, hbuf, NN * HH);

    // layer 1: h1 = tanh(spmm(x) @ W0)  (fp16)
    spmm_h16<<<NN / 4, 256, 0, stream>>>(hbuf, esrc, ew, rp, sbuf);
    gemm128_tanh<<<(NN + 127) / 128, 256, 0, stream>>>(sbuf, W0, hbuf);
    // layer 2: h2 = tanh(spmm(h1) @ W1) (fp16)
    spmm_h16<<<NN / 4, 256, 0, stream>>>(hbuf, esrc, ew, rp, sbuf);
    gemm128_tanh<<<(NN + 127) / 128, 256, 0, stream>>>(sbuf, W1, hbuf);
    // layer 3 reordered: g = h2 @ W2 (fp16, no tanh); out = tanh(spmm(g))
    gemm40_f16<<<(NN + 127) / 128, 256, 0, stream>>>(hbuf, W2, gbuf);
    spmm40_tanh<<<NN / 4, 256, 0, stream>>>(gbuf, esrc, ew, rp, out);
}

// Round 3
// 498.778 us; speedup vs baseline: 3.1082x; 1.1713x over previous
//
#include <hip/hip_runtime.h>
#include <hip/hip_fp16.h>

#define NN 100000
#define NPAD 100096   // 64*1564, covers all gemm tiles
#define EE 3200000
#define HH 128
#define CC 40

typedef _Float16 f16x8 __attribute__((ext_vector_type(8)));
typedef float f32x4 __attribute__((ext_vector_type(4)));

// rp[i] = lower_bound(edge_dst, i) — edge_dst is sorted.
__global__ void build_rp(const int* __restrict__ dst, int* __restrict__ rp) {
    int i = blockIdx.x * blockDim.x + threadIdx.x;
    if (i > NN) return;
    int lo = 0, hi = EE;
    while (lo < hi) {
        int mid = (lo + hi) >> 1;
        if (dst[mid] < i) lo = mid + 1; else hi = mid;
    }
    rp[i] = lo;
}

// f32 -> fp16, 8 elements/thread.
__global__ __launch_bounds__(256) void f32_to_f16(const float* __restrict__ in,
                                                  __half* __restrict__ out, int n) {
    int base = (blockIdx.x * 256 + threadIdx.x) * 8;
    if (base >= n) return;
    float4 a = *(const float4*)(in + base);
    float4 b = *(const float4*)(in + base + 4);
    __half2 h[4];
    h[0] = __floats2half2_rn(a.x, a.y);
    h[1] = __floats2half2_rn(a.z, a.w);
    h[2] = __floats2half2_rn(b.x, b.y);
    h[3] = __floats2half2_rn(b.z, b.w);
    *(float4*)(out + base) = *(float4*)h;
}

// Build fp16 transposed weights: W0t,W1t [128][128]; W2t [48][128] zero-padded.
__global__ __launch_bounds__(256) void prep_weights(const float* __restrict__ W0,
                                                    const float* __restrict__ W1,
                                                    const float* __restrict__ W2,
                                                    __half* __restrict__ W0t,
                                                    __half* __restrict__ W1t,
                                                    __half* __restrict__ W2t) {
    int i = blockIdx.x * 256 + threadIdx.x;
    if (i < HH * HH) {
        int c = i >> 7, k = i & 127;
        W0t[i] = __float2half_rn(W0[k * HH + c]);
        W1t[i] = __float2half_rn(W1[k * HH + c]);
    }
    if (i < 48 * HH) {
        int c = i >> 7, k = i & 127;
        W2t[i] = __float2half_rn(c < CC ? W2[k * CC + c] : 0.f);
    }
}

// One wave per node, 4 nodes/block. Lane t owns features 2t,2t+1 (half2).
// fp16 gather rows (256B/edge), f32 accumulate, fp16 out [NN][128].
__global__ __launch_bounds__(256) void spmm_h16(const __half* __restrict__ h,
                                                const int* __restrict__ src,
                                                const float* __restrict__ w,
                                                const int* __restrict__ rp,
                                                __half* __restrict__ out) {
    int node = blockIdx.x * 4 + (threadIdx.x >> 6);
    int t = threadIdx.x & 63;
    if (node >= NN) return;
    int e0 = __builtin_amdgcn_readfirstlane(rp[node]);
    int e1 = __builtin_amdgcn_readfirstlane(rp[node + 1]);
    const __half2* __restrict__ h2 = (const __half2*)h;
    float accx = 0.f, accy = 0.f;
    int e = e0;
    for (; e + 8 <= e1; e += 8) {
        int s[8]; float wv[8]; __half2 r[8];
#pragma unroll
        for (int j = 0; j < 8; ++j) { s[j] = src[e + j]; wv[j] = w[e + j]; }
#pragma unroll
        for (int j = 0; j < 8; ++j) r[j] = h2[(size_t)s[j] * 64 + t];
#pragma unroll
        for (int j = 0; j < 8; ++j) {
            float2 f = __half22float2(r[j]);
            accx = fmaf(wv[j], f.x, accx);
            accy = fmaf(wv[j], f.y, accy);
        }
    }
    for (; e < e1; ++e) {
        int s = src[e]; float ww = w[e];
        float2 f = __half22float2(h2[(size_t)s * 64 + t]);
        accx = fmaf(ww, f.x, accx); accy = fmaf(ww, f.y, accy);
    }
    ((__half2*)out)[(size_t)node * 64 + t] = __floats2half2_rn(accx, accy);
}

// spmm over 40-wide fp16 rows (80B/edge) + tanh, f32 out [NN][40] (final output).
__global__ __launch_bounds__(256) void spmm40_tanh(const __half* __restrict__ g,
                                                   const int* __restrict__ src,
                                                   const float* __restrict__ w,
                                                   const int* __restrict__ rp,
                                                   float* __restrict__ out) {
    int node = blockIdx.x * 4 + (threadIdx.x >> 6);
    int t = threadIdx.x & 63;
    if (node >= NN) return;
    int e0 = __builtin_amdgcn_readfirstlane(rp[node]);
    int e1 = __builtin_amdgcn_readfirstlane(rp[node + 1]);
    const __half2* __restrict__ g2 = (const __half2*)g;
    int tt = t < 20 ? t : 0;  // lanes >=20 discarded
    float accx = 0.f, accy = 0.f;
    int e = e0;
    for (; e + 8 <= e1; e += 8) {
        int s[8]; float wv[8]; __half2 r[8];
#pragma unroll
        for (int j = 0; j < 8; ++j) { s[j] = src[e + j]; wv[j] = w[e + j]; }
#pragma unroll
        for (int j = 0; j < 8; ++j) r[j] = g2[(size_t)s[j] * 20 + tt];
#pragma unroll
        for (int j = 0; j < 8; ++j) {
            float2 f = __half22float2(r[j]);
            accx = fmaf(wv[j], f.x, accx);
            accy = fmaf(wv[j], f.y, accy);
        }
    }
    for (; e < e1; ++e) {
        int s = src[e]; float ww = w[e];
        float2 f = __half22float2(g2[(size_t)s * 20 + tt]);
        accx = fmaf(ww, f.x, accx); accy = fmaf(ww, f.y, accy);
    }
    if (t < 20)
        *(float2*)(out + (size_t)node * CC + 2 * t) = make_float2(tanhf(accx), tanhf(accy));
}

// MFMA fp16 GEMM + tanh: out[r][c] = tanh(A[r][:] @ W[:][c]); Wt is [128][128] = W^T.
// Wave handles 16 rows x 128 cols. No LDS; Wt is L2-resident.
__global__ __launch_bounds__(256) void gemm_mfma_tanh(const __half* __restrict__ A,
                                                      const __half* __restrict__ Wt,
                                                      __half* __restrict__ out) {
    int wave = threadIdx.x >> 6, l = threadIdx.x & 63;
    int r0 = blockIdx.x * 64 + wave * 16;
    int lr = l & 15, lg = l >> 4;
    const _Float16* Af = (const _Float16*)A;
    const _Float16* Wf = (const _Float16*)Wt;
    int arow = r0 + lr;  // < NPAD by construction
    f16x8 a[4];
#pragma unroll
    for (int kb = 0; kb < 4; ++kb)
        a[kb] = *(const f16x8*)(Af + (size_t)arow * HH + kb * 32 + lg * 8);
#pragma unroll
    for (int ct = 0; ct < 8; ++ct) {
        f32x4 acc = {0.f, 0.f, 0.f, 0.f};
#pragma unroll
        for (int kb = 0; kb < 4; ++kb) {
            f16x8 b = *(const f16x8*)(Wf + (size_t)(ct * 16 + lr) * HH + kb * 32 + lg * 8);
            acc = __builtin_amdgcn_mfma_f32_16x16x32_f16(a[kb], b, acc, 0, 0, 0);
        }
#pragma unroll
        for (int r = 0; r < 4; ++r) {
            int row = r0 + lg * 4 + r;
            if (row < NN)
                out[(size_t)row * HH + ct * 16 + lr] = __float2half_rn(tanhf(acc[r]));
        }
    }
}

// MFMA fp16 GEMM, no tanh: g[r][c] = A[r][:] @ W2[:][c], c < 40. W2t is [48][128].
__global__ __launch_bounds__(256) void gemm40_mfma(const __half* __restrict__ A,
                                                   const __half* __restrict__ Wt,
                                                   __half* __restrict__ out) {
    int wave = threadIdx.x >> 6, l = threadIdx.x & 63;
    int r0 = blockIdx.x * 64 + wave * 16;
    int lr = l & 15, lg = l >> 4;
    const _Float16* Af = (const _Float16*)A;
    const _Float16* Wf = (const _Float16*)Wt;
    int arow = r0 + lr;
    f16x8 a[4];
#pragma unroll
    for (int kb = 0; kb < 4; ++kb)
        a[kb] = *(const f16x8*)(Af + (size_t)arow * HH + kb * 32 + lg * 8);
#pragma unroll
    for (int ct = 0; ct < 3; ++ct) {
        f32x4 acc = {0.f, 0.f, 0.f, 0.f};
#pragma unroll
        for (int kb = 0; kb < 4; ++kb) {
            f16x8 b = *(const f16x8*)(Wf + (size_t)(ct * 16 + lr) * HH + kb * 32 + lg * 8);
            acc = __builtin_amdgcn_mfma_f32_16x16x32_f16(a[kb], b, acc, 0, 0, 0);
        }
        int col = ct * 16 + lr;
#pragma unroll
        for (int r = 0; r < 4; ++r) {
            int row = r0 + lg * 4 + r;
            if (row < NN && col < CC)
                out[(size_t)row * CC + col] = __float2half_rn(acc[r]);
        }
    }
}

extern "C" void kernel_launch(void* const* d_in, const int* in_sizes, int n_in,
                              void* d_out, int out_size, void* d_ws, size_t ws_size,
                              hipStream_t stream) {
    const float* x    = (const float*)d_in[0];
    const int*   esrc = (const int*)d_in[1];
    const int*   edst = (const int*)d_in[2];
    const float* ew   = (const float*)d_in[3];
    const float* W0   = (const float*)d_in[4];
    const float* W1   = (const float*)d_in[5];
    const float* W2   = (const float*)d_in[6];
    float* out = (float*)d_out;

    char* ws = (char*)d_ws;
    size_t off = 0;
    int* rp = (int*)(ws + off);          off += (((size_t)(NN + 1) * 4) + 511) & ~(size_t)511;
    __half* xh = (__half*)(ws + off);    off += (size_t)NPAD * HH * sizeof(__half);
    __half* sA = (__half*)(ws + off);    off += (size_t)NPAD * HH * sizeof(__half);
    __half* hb = (__half*)(ws + off);    off += (size_t)NPAD * HH * sizeof(__half);
    __half* gb = (__half*)(ws + off);    off += (size_t)NPAD * CC * sizeof(__half);
    __half* W0t = (__half*)(ws + off);   off += (size_t)HH * HH * sizeof(__half);
    __half* W1t = (__half*)(ws + off);   off += (size_t)HH * HH * sizeof(__half);
    __half* W2t = (__half*)(ws + off);   off += (size_t)48 * HH * sizeof(__half);

    build_rp<<<(NN + 256) / 256, 256, 0, stream>>>(edst, rp);
    f32_to_f16<<<(NN * HH) / (256 * 8), 256, 0, stream>>>(x, xh, NN * HH);
    prep_weights<<<64, 256, 0, stream>>>(W0, W1, W2, W0t, W1t, W2t);

    int gemm_grid = NPAD / 64;
    // layer 1: h1 = tanh(spmm(x) @ W0)
    spmm_h16<<<NN / 4, 256, 0, stream>>>(xh, esrc, ew, rp, sA);
    gemm_mfma_tanh<<<gemm_grid, 256, 0, stream>>>(sA, W0t, hb);
    // layer 2: h2 = tanh(spmm(h1) @ W1)
    spmm_h16<<<NN / 4, 256, 0, stream>>>(hb, esrc, ew, rp, sA);
    gemm_mfma_tanh<<<gemm_grid, 256, 0, stream>>>(sA, W1t, hb);
    // layer 3 reordered: g = h2 @ W2 (no tanh); out = tanh(spmm(g))
    gemm40_mfma<<<gemm_grid, 256, 0, stream>>>(hb, W2t, gb);
    spmm40_tanh<<<NN / 4, 256, 0, stream>>>(gb, esrc, ew, rp, out);
}